// Round 15
// baseline (306.968 us; speedup 1.0000x reference)
//
#include <hip/hip_runtime.h>
#include <cstdint>

static constexpr float kEps  = 1e-5f;
static constexpr float kBeta = 0.1f;

typedef __attribute__((ext_vector_type(8))) short bf16x8;
typedef __attribute__((ext_vector_type(4))) float f32x4;
typedef __attribute__((ext_vector_type(2))) float f32x2;
typedef __attribute__((ext_vector_type(4))) _Float16 f16x4;

__device__ __forceinline__ ushort f2bf(float f){
  uint u = __float_as_uint(f);
  u += 0x7fff + ((u>>16)&1);      // round-to-nearest-even
  return (ushort)(u>>16);
}
__device__ __forceinline__ float bf2f(ushort h){
  return __uint_as_float(((uint)h)<<16);
}

// ---------------- CSR build (XCD-binned) ----------------
__global__ void k_hist_bin(const int* __restrict__ row, int* __restrict__ deg,
                           int E, int NR){
  const int p  = blockIdx.x & 7;
  const int q  = blockIdx.x >> 3;
  const int NQ = gridDim.x >> 3;
  const int lo = p*NR, hi = lo + NR;
  for (int e = q*256 + threadIdx.x; e < E; e += NQ*256){
    int r = row[e];
    if (r >= lo && r < hi) atomicAdd(&deg[r], 1);
  }
}

__global__ void k_scan_block(const int* __restrict__ deg, int* __restrict__ start,
                             int* __restrict__ bsum, int N){
  __shared__ int s[256];
  int t = threadIdx.x;
  int i = blockIdx.x*256 + t;
  int v = (i < N) ? deg[i] : 0;
  s[t] = v; __syncthreads();
  for (int off=1; off<256; off<<=1){
    int add = (t >= off) ? s[t-off] : 0;
    __syncthreads();
    s[t] += add;
    __syncthreads();
  }
  if (i < N) start[i+1] = s[t];
  if (t == 255) bsum[blockIdx.x] = s[255];
}

__global__ void k_scan_bsum(const int* __restrict__ bsum, int* __restrict__ boff, int nb){
  __shared__ int s[256];
  int t = threadIdx.x;
  int v = (t < nb) ? bsum[t] : 0;
  s[t] = v; __syncthreads();
  for (int off=1; off<256; off<<=1){
    int add = (t >= off) ? s[t-off] : 0;
    __syncthreads();
    s[t] += add;
    __syncthreads();
  }
  if (t < nb) boff[t] = s[t] - v;   // exclusive
}

__global__ void k_scan_add(int* __restrict__ start, const int* __restrict__ boff, int N){
  int i = blockIdx.x*256 + threadIdx.x;
  if (i < N) start[i+1] += boff[blockIdx.x];
  if (blockIdx.x==0 && threadIdx.x==0) start[0] = 0;
}

__global__ void k_fill_bin(const int* __restrict__ row, const int* __restrict__ col,
                           const int* __restrict__ start, int* __restrict__ cursor,
                           int* __restrict__ colcsr, int E, int NR){
  const int p  = blockIdx.x & 7;
  const int q  = blockIdx.x >> 3;
  const int NQ = gridDim.x >> 3;
  const int lo = p*NR, hi = lo + NR;
  for (int e = q*256 + threadIdx.x; e < E; e += NQ*256){
    int r = row[e];
    if (r >= lo && r < hi){
      int pos = atomicAdd(&cursor[r], 1);
      colcsr[start[r] + pos] = col[e];
    }
  }
}

__global__ void k_rowfill(const int* __restrict__ start, int* __restrict__ rowcsr, int N){
  int n = blockIdx.x*256 + threadIdx.x;
  if (n < N){
    int s0 = start[n], s1 = start[n+1];
    for (int i=s0; i<s1; ++i) rowcsr[i] = n;
  }
}

// ---------------- W1 -> bf16, k-chunk-contiguous layout ----------------
__global__ void k_prep_w1(const float* __restrict__ W1, ushort* __restrict__ W1s){
  int i = blockIdx.x*256 + threadIdx.x;   // i = k*256 + col
  int k = i >> 8, col = i & 255;
  W1s[(k>>5)*8192 + col*32 + (k&31)] = f2bf(W1[i]);
}

// ---- [256][64] fp32 weight -> split hi/lo bf16, layout [kc][col][kk] ----
__global__ void k_prep_w64(const float* __restrict__ W,
                           ushort* __restrict__ Wh, ushort* __restrict__ Wl){
  int i = blockIdx.x*256 + threadIdx.x;   // i = k*64 + col, 16384 total
  int k = i >> 6, col = i & 63;
  int dst = (k>>5)*2048 + col*32 + (k&31);
  float w = W[i];
  ushort hb = f2bf(w);
  Wh[dst] = hb;
  Wl[dst] = f2bf(w - bf2f(hb));
}

// ---------------- GEMM1 (MFMA, split-x bf16) + bias + relu + LN -> ego(bf16) ----
__global__ __launch_bounds__(256) void k_gemm1_mfma(const float* __restrict__ x,
    const ushort* __restrict__ W1s, const float* __restrict__ b1,
    const float* __restrict__ g, const float* __restrict__ bb,
    ushort* __restrict__ ego, int N){
  __shared__ ushort xh[64][40];
  __shared__ ushort xl[64][40];
  __shared__ ushort wl[256][40];
  __shared__ float psum[64][4], psq[64][4];
  __shared__ float mub[64], ivb[64];

  const int tid = threadIdx.x;
  const int n0  = blockIdx.x*64;
  const int w   = tid>>6;
  const int l   = tid&63;
  const int l15 = l&15;
  const int lg  = l>>4;            // 0..3
  const int cb  = w*64;            // wave col base
  const int sxr = tid>>2;          // x row 0..63
  const int sxk = (tid&3)*8;       // k offset {0,8,16,24}

  f32x4 acc[4][4];
  #pragma unroll
  for (int rt=0;rt<4;rt++)
    #pragma unroll
    for (int ct=0;ct<4;ct++)
      acc[rt][ct] = (f32x4){0.f,0.f,0.f,0.f};

  for (int kc=0; kc<8; ++kc){
    if (kc) __syncthreads();
    const float* xp = &x[(size_t)min(n0+sxr, N-1)*256 + kc*32 + sxk];
    float4 v0 = *reinterpret_cast<const float4*>(xp);
    float4 v1 = *reinterpret_cast<const float4*>(xp+4);
    const float vv[8] = {v0.x,v0.y,v0.z,v0.w,v1.x,v1.y,v1.z,v1.w};
    bf16x8 hv, lv;
    #pragma unroll
    for (int j=0;j<8;j++){
      ushort hb = f2bf(vv[j]);
      hv[j] = (short)hb;
      lv[j] = (short)f2bf(vv[j] - bf2f(hb));
    }
    *reinterpret_cast<bf16x8*>(&xh[sxr][sxk]) = hv;
    *reinterpret_cast<bf16x8*>(&xl[sxr][sxk]) = lv;
    const ushort* wp = &W1s[kc*8192 + tid*32];
    #pragma unroll
    for (int s=0;s<4;s++)
      *reinterpret_cast<bf16x8*>(&wl[tid][s*8]) =
          *reinterpret_cast<const bf16x8*>(wp + s*8);
    __syncthreads();
    bf16x8 ah[4], al[4];
    #pragma unroll
    for (int rt=0;rt<4;rt++){
      ah[rt] = *reinterpret_cast<const bf16x8*>(&xh[rt*16+l15][lg*8]);
      al[rt] = *reinterpret_cast<const bf16x8*>(&xl[rt*16+l15][lg*8]);
    }
    #pragma unroll
    for (int ct=0;ct<4;ct++){
      bf16x8 bv = *reinterpret_cast<const bf16x8*>(&wl[cb+ct*16+l15][lg*8]);
      #pragma unroll
      for (int rt=0;rt<4;rt++){
        acc[rt][ct] = __builtin_amdgcn_mfma_f32_16x16x32_bf16(al[rt], bv, acc[rt][ct], 0,0,0);
        acc[rt][ct] = __builtin_amdgcn_mfma_f32_16x16x32_bf16(ah[rt], bv, acc[rt][ct], 0,0,0);
      }
    }
  }

  float b1v[4], gv[4], bbv[4];
  #pragma unroll
  for (int ct=0;ct<4;ct++){
    int col = cb + ct*16 + l15;
    b1v[ct] = b1[col]; gv[ct] = g[col]; bbv[ct] = bb[col];
  }
  #pragma unroll
  for (int rt=0;rt<4;rt++)
    #pragma unroll
    for (int ct=0;ct<4;ct++)
      #pragma unroll
      for (int r=0;r<4;r++)
        acc[rt][ct][r] = fmaxf(acc[rt][ct][r] + b1v[ct], 0.f);

  #pragma unroll
  for (int rt=0;rt<4;rt++){
    #pragma unroll
    for (int r=0;r<4;r++){
      float s = acc[rt][0][r]+acc[rt][1][r]+acc[rt][2][r]+acc[rt][3][r];
      float q = acc[rt][0][r]*acc[rt][0][r]+acc[rt][1][r]*acc[rt][1][r]
              + acc[rt][2][r]*acc[rt][2][r]+acc[rt][3][r]*acc[rt][3][r];
      #pragma unroll
      for (int o=1;o<16;o<<=1){ s += __shfl_xor(s,o); q += __shfl_xor(q,o); }
      if (l15 == 0){
        int row = rt*16 + lg*4 + r;
        psum[row][w] = s; psq[row][w] = q;
      }
    }
  }
  __syncthreads();
  if (tid < 64){
    float s = psum[tid][0]+psum[tid][1]+psum[tid][2]+psum[tid][3];
    float q = psq[tid][0]+psq[tid][1]+psq[tid][2]+psq[tid][3];
    float mu  = s * (1.f/256.f);
    float var = q * (1.f/256.f) - mu*mu;
    mub[tid] = mu;
    ivb[tid] = rsqrtf(fmaxf(var, 0.f) + kEps);
  }
  __syncthreads();
  #pragma unroll
  for (int rt=0;rt<4;rt++){
    #pragma unroll
    for (int r=0;r<4;r++){
      int row  = rt*16 + lg*4 + r;
      int grow = n0 + row;
      if (grow < N){
        float mu = mub[row], inv = ivb[row];
        size_t base = (size_t)grow*256 + cb + l15;
        #pragma unroll
        for (int ct=0;ct<4;ct++)
          ego[base + ct*16] = f2bf((acc[rt][ct][r]-mu)*inv*gv[ct] + bbv[ct]);
      }
    }
  }
}

// ------- MFMA 256->64 GEMM (bf16 x, split W) -> bf16 h -------
__global__ __launch_bounds__(256) void k_hgemm_mfma(const ushort* __restrict__ x,
    const ushort* __restrict__ Wh, const ushort* __restrict__ Wl,
    ushort* __restrict__ h, int N){
  __shared__ ushort xs[64][40];
  __shared__ ushort wh[64][40];
  __shared__ ushort wl[64][40];
  const int tid = threadIdx.x;
  const int n0  = blockIdx.x*64;
  const int w   = tid>>6;
  const int l15 = tid&15;
  const int lg  = (tid&63)>>4;
  const int sxr = tid>>2;
  const int sxk = (tid&3)*8;

  f32x4 acc[4];
  #pragma unroll
  for (int ct=0;ct<4;ct++) acc[ct] = (f32x4){0.f,0.f,0.f,0.f};

  for (int kc=0; kc<8; ++kc){
    if (kc) __syncthreads();
    *reinterpret_cast<bf16x8*>(&xs[sxr][sxk]) =
        *reinterpret_cast<const bf16x8*>(&x[(size_t)min(n0+sxr, N-1)*256 + kc*32 + sxk]);
    int src = kc*2048 + sxr*32 + sxk;
    *reinterpret_cast<bf16x8*>(&wh[sxr][sxk]) =
        *reinterpret_cast<const bf16x8*>(&Wh[src]);
    *reinterpret_cast<bf16x8*>(&wl[sxr][sxk]) =
        *reinterpret_cast<const bf16x8*>(&Wl[src]);
    __syncthreads();
    bf16x8 ah = *reinterpret_cast<const bf16x8*>(&xs[w*16+l15][lg*8]);
    #pragma unroll
    for (int ct=0;ct<4;ct++){
      bf16x8 bh = *reinterpret_cast<const bf16x8*>(&wh[ct*16+l15][lg*8]);
      bf16x8 bl = *reinterpret_cast<const bf16x8*>(&wl[ct*16+l15][lg*8]);
      acc[ct] = __builtin_amdgcn_mfma_f32_16x16x32_bf16(ah, bl, acc[ct], 0,0,0);
      acc[ct] = __builtin_amdgcn_mfma_f32_16x16x32_bf16(ah, bh, acc[ct], 0,0,0);
    }
  }
  #pragma unroll
  for (int r=0;r<4;r++){
    int grow = n0 + w*16 + lg*4 + r;
    if (grow < N){
      #pragma unroll
      for (int ct=0;ct<4;ct++)
        h[(size_t)grow*64 + ct*16 + l15] = f2bf(acc[ct][r]);
    }
  }
}

// ------- MFMA 256->64 GEMM + bias + log_softmax -> out -------
__global__ __launch_bounds__(256) void k_out_mfma(const ushort* __restrict__ x,
    const ushort* __restrict__ Wh, const ushort* __restrict__ Wl,
    const float* __restrict__ b2, float* __restrict__ out, int N){
  __shared__ ushort xs[64][40];
  __shared__ ushort wh[64][40];
  __shared__ ushort wl[64][40];
  const int tid = threadIdx.x;
  const int n0  = blockIdx.x*64;
  const int w   = tid>>6;
  const int l15 = tid&15;
  const int lg  = (tid&63)>>4;
  const int sxr = tid>>2;
  const int sxk = (tid&3)*8;

  f32x4 acc[4];
  #pragma unroll
  for (int ct=0;ct<4;ct++) acc[ct] = (f32x4){0.f,0.f,0.f,0.f};

  for (int kc=0; kc<8; ++kc){
    if (kc) __syncthreads();
    *reinterpret_cast<bf16x8*>(&xs[sxr][sxk]) =
        *reinterpret_cast<const bf16x8*>(&x[(size_t)min(n0+sxr, N-1)*256 + kc*32 + sxk]);
    int src = kc*2048 + sxr*32 + sxk;
    *reinterpret_cast<bf16x8*>(&wh[sxr][sxk]) =
        *reinterpret_cast<const bf16x8*>(&Wh[src]);
    *reinterpret_cast<bf16x8*>(&wl[sxr][sxk]) =
        *reinterpret_cast<const bf16x8*>(&Wl[src]);
    __syncthreads();
    bf16x8 ah = *reinterpret_cast<const bf16x8*>(&xs[w*16+l15][lg*8]);
    #pragma unroll
    for (int ct=0;ct<4;ct++){
      bf16x8 bh = *reinterpret_cast<const bf16x8*>(&wh[ct*16+l15][lg*8]);
      bf16x8 bl = *reinterpret_cast<const bf16x8*>(&wl[ct*16+l15][lg*8]);
      acc[ct] = __builtin_amdgcn_mfma_f32_16x16x32_bf16(ah, bl, acc[ct], 0,0,0);
      acc[ct] = __builtin_amdgcn_mfma_f32_16x16x32_bf16(ah, bh, acc[ct], 0,0,0);
    }
  }

  float b2v[4];
  #pragma unroll
  for (int ct=0;ct<4;ct++) b2v[ct] = b2[ct*16+l15];

  #pragma unroll
  for (int r=0;r<4;r++){
    float v[4];
    #pragma unroll
    for (int ct=0;ct<4;ct++) v[ct] = acc[ct][r] + b2v[ct];
    float mx = fmaxf(fmaxf(v[0],v[1]), fmaxf(v[2],v[3]));
    #pragma unroll
    for (int o=1;o<16;o<<=1) mx = fmaxf(mx, __shfl_xor(mx,o));
    float sm = __expf(v[0]-mx)+__expf(v[1]-mx)+__expf(v[2]-mx)+__expf(v[3]-mx);
    #pragma unroll
    for (int o=1;o<16;o<<=1) sm += __shfl_xor(sm,o);
    float ls = __logf(sm);
    int grow = n0 + w*16 + lg*4 + r;
    if (grow < N){
      #pragma unroll
      for (int ct=0;ct<4;ct++)
        out[(size_t)grow*64 + ct*16 + l15] = (v[ct]-mx) - ls;
    }
  }
}

// ---------------- edge attention, lane = edge (CSR order), fp16 out ----------------
__global__ __launch_bounds__(256) void k_edge(
    const ushort* __restrict__ h,
    const int* __restrict__ rowcsr, const int* __restrict__ colcsr,
    const float* __restrict__ attw,    // [64][4]
    f16x4* __restrict__ a_csr, int E){
  int e = blockIdx.x*256 + threadIdx.x;
  if (e >= E) return;
  int r = rowcsr[e], c = colcsr[e];
  const uint4* hrp = reinterpret_cast<const uint4*>(h + (size_t)r*64);
  const uint4* hcp = reinterpret_cast<const uint4*>(h + (size_t)c*64);

  float q0=0.f, q1=0.f, q2=0.f, q3=0.f;
  #pragma unroll
  for (int s=0; s<8; ++s){
    uint4 hr4 = hrp[s];
    uint4 hc4 = hcp[s];
    const uint hru[4] = {hr4.x, hr4.y, hr4.z, hr4.w};
    const uint hcu[4] = {hc4.x, hc4.y, hc4.z, hc4.w};
    #pragma unroll
    for (int t=0; t<4; ++t){
      float hrl = __uint_as_float(hru[t]<<16);
      float hrh = __uint_as_float(hru[t]&0xffff0000u);
      float hcl = __uint_as_float(hcu[t]<<16);
      float hch = __uint_as_float(hcu[t]&0xffff0000u);
      float pl = fmaxf(fmaf(0.5f, hrl, hcl), 0.f);
      float ph = fmaxf(fmaf(0.5f, hrh, hch), 0.f);
      int d = s*8 + t*2;
      float4 w0 = *reinterpret_cast<const float4*>(&attw[(d  )*4]);  // uniform
      float4 w1 = *reinterpret_cast<const float4*>(&attw[(d+1)*4]);  // uniform
      q0 = fmaf(pl, w0.x, q0); q1 = fmaf(pl, w0.y, q1);
      q2 = fmaf(pl, w0.z, q2); q3 = fmaf(pl, w0.w, q3);
      q0 = fmaf(ph, w1.x, q0); q1 = fmaf(ph, w1.y, q1);
      q2 = fmaf(ph, w1.z, q2); q3 = fmaf(ph, w1.w, q3);
    }
  }
  float m = fmaxf(fmaxf(q0,q1), fmaxf(q2,q3));
  float e0=__expf(q0-m), e1=__expf(q1-m), e2=__expf(q2-m), e3=__expf(q3-m);
  float inv = 1.f/(e0+e1+e2+e3);
  f16x4 av;
  av[0] = (_Float16)(e0*inv); av[1] = (_Float16)(e1*inv);
  av[2] = (_Float16)(e2*inv); av[3] = (_Float16)(e3*inv);
  a_csr[e] = av;
}

// ------- aggregate + relu + LN + residual (LDS-staged adjacency) -------
// Wave per node. Adjacency (col, a) staged in wave-private LDS (exec-mask
// safe, unlike ds_bpermute). Inner loop: 4-wide batched h-gathers, the only
// global accesses. Accumulate as float2 (v_pk_fma_f32).
__global__ __launch_bounds__(256) void k_agg(
    const ushort* __restrict__ h,      // [N][64] bf16
    const int* __restrict__ colcsr, const int* __restrict__ start,
    const f16x4* __restrict__ a_csr,
    const ushort* __restrict__ ego,    // [N][256] bf16
    const float* __restrict__ g, const float* __restrict__ b,
    ushort* __restrict__ xout, int N){
  __shared__ int   s_col[4][64];
  __shared__ uint2 s_a[4][64];
  const int lane = threadIdx.x & 63;
  const int wid  = threadIdx.x >> 6;
  const int grp  = lane >> 4;
  const int l15  = lane & 15;
  const int n = blockIdx.x*4 + wid;
  if (n >= N) return;

  const int s0 = start[n], s1 = start[n+1];
  const int deg = s1 - s0;
  const int dcap = min(deg, 64);
  const size_t hoff = (size_t)l15*4;

  // stage adjacency into wave-private LDS (same-wave write->read, no barrier)
  if (lane < dcap){
    s_col[wid][lane] = colcsr[s0 + lane];
    f16x4 a4 = a_csr[s0 + lane];
    s_a[wid][lane] = *reinterpret_cast<uint2*>(&a4);
  }

  f32x2 acc2[4][2];
  #pragma unroll
  for (int c=0;c<4;c++){ acc2[c][0]=(f32x2){0.f,0.f}; acc2[c][1]=(f32x2){0.f,0.f}; }

  auto edge_acc = [&](int cn, uint2 uu){
    ushort4 hv = *reinterpret_cast<const ushort4*>(&h[(size_t)cn*64 + hoff]);
    f32x2 hlo = (f32x2){bf2f(hv.x), bf2f(hv.y)};
    f32x2 hhi = (f32x2){bf2f(hv.z), bf2f(hv.w)};
    f16x4 af = *reinterpret_cast<f16x4*>(&uu);
    #pragma unroll
    for (int c=0;c<4;c++){
      float ac = (float)af[c];
      f32x2 av = (f32x2){ac, ac};
      acc2[c][0] += av * hlo;
      acc2[c][1] += av * hhi;
    }
  };

  // 4-wide main loop over staged slots (group grp owns slots grp, grp+4, ...)
  int t = grp;
  for (; t + 12 < dcap; t += 16){
    int  c0 = s_col[wid][t],   c1 = s_col[wid][t+4];
    int  c2 = s_col[wid][t+8], c3 = s_col[wid][t+12];
    uint2 a0 = s_a[wid][t],    a1 = s_a[wid][t+4];
    uint2 a2 = s_a[wid][t+8],  a3 = s_a[wid][t+12];
    edge_acc(c0,a0); edge_acc(c1,a1); edge_acc(c2,a2); edge_acc(c3,a3);
  }
  for (; t < dcap; t += 4)
    edge_acc(s_col[wid][t], s_a[wid][t]);
  // rare deg>64 tail: direct loads
  for (int i = s0 + 64 + grp; i < s1; i += 4){
    int cn = colcsr[i];
    f16x4 a4 = a_csr[i];
    uint2 uu = *reinterpret_cast<uint2*>(&a4);
    edge_acc(cn, uu);
  }

  float acc[4][4];
  #pragma unroll
  for (int c=0;c<4;c++){
    acc[c][0]=acc2[c][0].x; acc[c][1]=acc2[c][0].y;
    acc[c][2]=acc2[c][1].x; acc[c][3]=acc2[c][1].y;
  }

  #pragma unroll
  for (int c=0;c<4;c++)
    #pragma unroll
    for (int j=0;j<4;j++){
      float v = acc[c][j];
      v += __shfl_xor(v,16);
      v += __shfl_xor(v,32);
      acc[c][j] = fmaxf(v, 0.f);   // relu
    }

  float s=0.f, sq=0.f;
  #pragma unroll
  for (int c=0;c<4;c++)
    #pragma unroll
    for (int j=0;j<4;j++){ float v=acc[c][j]; s+=v; sq+=v*v; }
  #pragma unroll
  for (int o=1;o<16;o<<=1){ s += __shfl_xor(s,o); sq += __shfl_xor(sq,o); }
  float mu  = s * (1.f/256.f);
  float var = sq * (1.f/256.f) - mu*mu;
  float inv = rsqrtf(fmaxf(var,0.f) + kEps);

  int colb = grp*64 + l15*4;
  float4 gv  = *reinterpret_cast<const float4*>(&g[colb]);
  float4 bv  = *reinterpret_cast<const float4*>(&b[colb]);
  size_t base = (size_t)n*256 + colb;
  ushort4 ev = *reinterpret_cast<const ushort4*>(&ego[base]);
  ushort4 y;
  y.x = f2bf((1.f-kBeta)*((acc[grp][0]-mu)*inv*gv.x + bv.x) + kBeta*bf2f(ev.x));
  y.y = f2bf((1.f-kBeta)*((acc[grp][1]-mu)*inv*gv.y + bv.y) + kBeta*bf2f(ev.y));
  y.z = f2bf((1.f-kBeta)*((acc[grp][2]-mu)*inv*gv.z + bv.z) + kBeta*bf2f(ev.z));
  y.w = f2bf((1.f-kBeta)*((acc[grp][3]-mu)*inv*gv.w + bv.w) + kBeta*bf2f(ev.w));
  *reinterpret_cast<ushort4*>(&xout[base]) = y;
}

extern "C" void kernel_launch(void* const* d_in, const int* in_sizes, int n_in,
                              void* d_out, int out_size, void* d_ws, size_t ws_size,
                              hipStream_t stream){
  const float* x_in = (const float*)d_in[0];
  const int*   ei   = (const int*)d_in[1];
  const float* W1   = (const float*)d_in[2];
  const float* b1   = (const float*)d_in[3];
  const float* lin  = (const float*)d_in[4];
  const float* att  = (const float*)d_in[5];
  const float* lng  = (const float*)d_in[6];
  const float* lnb  = (const float*)d_in[7];
  const float* W2   = (const float*)d_in[8];
  const float* b2   = (const float*)d_in[9];
  float* out = (float*)d_out;

  const int N = in_sizes[0] / 256;   // 50000
  const int E = in_sizes[1] / 2;     // 800000
  const int* row = ei;
  const int* col = ei + E;

  char* basep = (char*)d_ws;
  size_t off = 0;
  auto alloc = [&](size_t bytes)->char*{
    char* p = basep + off;
    off += (bytes + 255) & ~(size_t)255;
    return p;
  };
  ushort* ego    = (ushort*)alloc((size_t)N*256*2);
  ushort* xbuf   = (ushort*)alloc((size_t)N*256*2);
  ushort* hbuf   = (ushort*)alloc((size_t)N*64*2);
  f16x4*  acsr   = (f16x4*) alloc((size_t)E*8);
  int*    startp = (int*)   alloc((size_t)(N+1)*4);
  int*    deg    = (int*)   alloc((size_t)N*4);   // also reused as cursor
  int*    rowcsr = (int*)   alloc((size_t)E*4);
  int*    colcsr = (int*)   alloc((size_t)E*4);
  int*    bsum   = (int*)   alloc(256*4);
  int*    boff   = (int*)   alloc(256*4);
  ushort* W1s    = (ushort*)alloc((size_t)256*256*2);
  ushort* linh   = (ushort*)alloc((size_t)2*16384*2);
  ushort* linl   = (ushort*)alloc((size_t)2*16384*2);
  ushort* W2h    = (ushort*)alloc((size_t)16384*2);
  ushort* W2l    = (ushort*)alloc((size_t)16384*2);

  int nbE = (E + 255)/256;   // 3125
  int nbN = (N + 255)/256;   // 196
  int nbT = (N + 63)/64;     // 782 tiles
  int NR  = (N + 7)/8;       // node range per XCD class

  // CSR build (binned hist + fill)
  hipMemsetAsync(deg, 0, (size_t)N*4, stream);
  k_hist_bin<<<1024,256,0,stream>>>(row, deg, E, NR);
  k_scan_block<<<nbN,256,0,stream>>>(deg, startp, bsum, N);
  k_scan_bsum<<<1,256,0,stream>>>(bsum, boff, nbN);
  k_scan_add<<<nbN,256,0,stream>>>(startp, boff, N);
  hipMemsetAsync(deg, 0, (size_t)N*4, stream);     // cursor
  k_fill_bin<<<1024,256,0,stream>>>(row, col, startp, deg, colcsr, E, NR);
  k_rowfill<<<nbN,256,0,stream>>>(startp, rowcsr, N);

  // weight prep
  k_prep_w1<<<256,256,0,stream>>>(W1, W1s);
  k_prep_w64<<<64,256,0,stream>>>(lin,          linh,          linl);
  k_prep_w64<<<64,256,0,stream>>>(lin + 16384,  linh + 16384,  linl + 16384);
  k_prep_w64<<<64,256,0,stream>>>(W2, W2h, W2l);

  // MFMA projection + bias + relu + LN -> ego (bf16)
  k_gemm1_mfma<<<nbT,256,0,stream>>>(x_in, W1s, b1, lng, lnb, ego, N);

  for (int L=0; L<2; ++L){
    const ushort* xsrc = (L == 0) ? ego : xbuf;
    k_hgemm_mfma<<<nbT,256,0,stream>>>(xsrc, linh + (size_t)L*16384,
                                       linl + (size_t)L*16384, hbuf, N);
    k_edge<<<nbE,256,0,stream>>>(hbuf, rowcsr, colcsr,
                                 att + (size_t)L*64*4, acsr, E);
    k_agg<<<(N+3)/4,256,0,stream>>>(hbuf, colcsr, startp, acsr, ego,
                                    lng + (size_t)(L+1)*256, lnb + (size_t)(L+1)*256,
                                    xbuf, N);
  }
  k_out_mfma<<<nbT,256,0,stream>>>(xbuf, W2h, W2l, b2, out, N);
}